// Round 1
// baseline (140.884 us; speedup 1.0000x reference)
//
#include <hip/hip_runtime.h>

#define NUM_IDS   16384
#define EMBED_DIM 128
#define INV_KPROB 1.25f

__global__ __launch_bounds__(128) void seg_embed_kernel(
    const int*   __restrict__ row_idx,
    const int*   __restrict__ col_idx,
    const float* __restrict__ data,
    const float* __restrict__ emb,
    const int*   __restrict__ keep,
    float*       __restrict__ out,
    int nnz)
{
    const int row = blockIdx.x;
    const int d   = threadIdx.x;

    // lower_bound(row) and lower_bound(row+1) in sorted row_idx.
    // All threads run it redundantly (uniform addresses -> cache broadcast).
    int lo = 0, hi = nnz;
    while (lo < hi) {
        int mid = (lo + hi) >> 1;
        if (row_idx[mid] < row) lo = mid + 1; else hi = mid;
    }
    const int start = lo;
    hi = nnz;
    while (lo < hi) {
        int mid = (lo + hi) >> 1;
        if (row_idx[mid] < row + 1) lo = mid + 1; else hi = mid;
    }
    const int end = lo;

    float acc = 0.0f;
    for (int i = start; i < end; ++i) {
        const int   c = col_idx[i];
        const float v = data[i] * ((float)keep[i] * INV_KPROB);
        acc = fmaf(v, emb[(long)c * EMBED_DIM + d], acc);
    }
    out[(long)row * EMBED_DIM + d] = acc;
}

extern "C" void kernel_launch(void* const* d_in, const int* in_sizes, int n_in,
                              void* d_out, int out_size, void* d_ws, size_t ws_size,
                              hipStream_t stream) {
    const int*   row_idx = (const int*)  d_in[0];
    const int*   col_idx = (const int*)  d_in[1];
    const float* data    = (const float*)d_in[2];
    const float* emb     = (const float*)d_in[3];
    const int*   keep    = (const int*)  d_in[4];
    float*       out     = (float*)d_out;
    const int    nnz     = in_sizes[0];

    seg_embed_kernel<<<NUM_IDS, 128, 0, stream>>>(
        row_idx, col_idx, data, emb, keep, out, nnz);
}

// Round 2
// 70.151 us; speedup vs baseline: 2.0083x; 2.0083x over previous
//
#include <hip/hip_runtime.h>

#define NUM_IDS   16384
#define EMBED_DIM 128
#define INV_KPROB 1.25f
#define WAVES_PER_BLOCK 4

// ---------------- Kernel 1: row_ptr from sorted row_idx ----------------
// ptr[r] = first index i with row_idx[i] >= r ; ptr[NUM_IDS] = nnz
__global__ void build_rowptr(const int* __restrict__ row_idx, int nnz,
                             int* __restrict__ ptr) {
    int i = blockIdx.x * blockDim.x + threadIdx.x;
    if (i >= nnz) return;
    int b = row_idx[i];
    if (i == 0) {
        for (int r = 0; r <= b; ++r) ptr[r] = 0;
    } else {
        int a = row_idx[i - 1];
        for (int r = a + 1; r <= b; ++r) ptr[r] = i;
    }
    if (i == nnz - 1) {
        for (int r = b + 1; r <= NUM_IDS; ++r) ptr[r] = nnz;
    }
}

// ---------------- Core accumulation (one wave = one output row) --------
__device__ __forceinline__ void accum_row(
    int row, int start, int end, int lane,
    const int* __restrict__ col_idx,
    const float* __restrict__ data,
    const int* __restrict__ keep,
    const float* __restrict__ emb,
    float* __restrict__ out)
{
    const int half = lane >> 5;        // 0 or 1
    const int q    = lane & 31;        // dim slice: dims [4q, 4q+3]
    const float* embq = emb + 4 * q;

    float4 acc = make_float4(0.f, 0.f, 0.f, 0.f);

    for (int base = start; base < end; base += 64) {
        // Each half-wave stages 32 entries' metadata (coalesced 128B loads).
        const int myi = base + (half << 5) + q;
        int   c = 0;
        float v = 0.f;
        if (myi < end) {
            c = col_idx[myi];
            v = data[myi] * ((float)keep[myi] * INV_KPROB);
        }
        int nh = end - (base + (half << 5));   // entries owned by my half
        if (nh > 32) nh = 32;
        for (int j = 0; j < nh; ++j) {
            const int   src = (half << 5) + j;          // broadcast within own half
            const int   cj  = __shfl(c, src, 64);
            const float vj  = __shfl(v, src, 64);
            const float4 e  = *reinterpret_cast<const float4*>(
                                  embq + (size_t)cj * EMBED_DIM);
            acc.x = fmaf(vj, e.x, acc.x);
            acc.y = fmaf(vj, e.y, acc.y);
            acc.z = fmaf(vj, e.z, acc.z);
            acc.w = fmaf(vj, e.w, acc.w);
        }
    }

    // Merge the two halves (lane q gets lane q+32's partial).
    acc.x += __shfl_xor(acc.x, 32, 64);
    acc.y += __shfl_xor(acc.y, 32, 64);
    acc.z += __shfl_xor(acc.z, 32, 64);
    acc.w += __shfl_xor(acc.w, 32, 64);

    if (half == 0) {
        *reinterpret_cast<float4*>(out + (size_t)row * EMBED_DIM + 4 * q) = acc;
    }
}

// ---------------- Kernel 2a: main path (row_ptr in d_ws) ----------------
__global__ __launch_bounds__(256) void seg_embed_ptr(
    const int* __restrict__ col_idx,
    const float* __restrict__ data,
    const float* __restrict__ emb,
    const int* __restrict__ keep,
    const int* __restrict__ ptr,
    float* __restrict__ out)
{
    const int lane = threadIdx.x & 63;
    const int wave = threadIdx.x >> 6;
    const int row  = blockIdx.x * WAVES_PER_BLOCK + wave;
    const int start = ptr[row];
    const int end   = ptr[row + 1];
    accum_row(row, start, end, lane, col_idx, data, keep, emb, out);
}

// ---------------- Kernel 2b: fallback (binary search, no scratch) -------
__global__ __launch_bounds__(256) void seg_embed_bs(
    const int* __restrict__ row_idx,
    const int* __restrict__ col_idx,
    const float* __restrict__ data,
    const float* __restrict__ emb,
    const int* __restrict__ keep,
    float* __restrict__ out, int nnz)
{
    const int lane = threadIdx.x & 63;
    const int wave = threadIdx.x >> 6;
    const int row  = blockIdx.x * WAVES_PER_BLOCK + wave;

    int lo = 0, hi = nnz;
    while (lo < hi) { int m = (lo + hi) >> 1; if (row_idx[m] < row) lo = m + 1; else hi = m; }
    const int start = lo;
    hi = nnz;
    while (lo < hi) { int m = (lo + hi) >> 1; if (row_idx[m] < row + 1) lo = m + 1; else hi = m; }
    const int end = lo;

    accum_row(row, start, end, lane, col_idx, data, keep, emb, out);
}

extern "C" void kernel_launch(void* const* d_in, const int* in_sizes, int n_in,
                              void* d_out, int out_size, void* d_ws, size_t ws_size,
                              hipStream_t stream) {
    const int*   row_idx = (const int*)  d_in[0];
    const int*   col_idx = (const int*)  d_in[1];
    const float* data    = (const float*)d_in[2];
    const float* emb     = (const float*)d_in[3];
    const int*   keep    = (const int*)  d_in[4];
    float*       out     = (float*)d_out;
    const int    nnz     = in_sizes[0];

    const size_t ptr_bytes = (size_t)(NUM_IDS + 1) * sizeof(int);
    const int    grid      = NUM_IDS / WAVES_PER_BLOCK;

    if (ws_size >= ptr_bytes) {
        int* ptr = (int*)d_ws;
        build_rowptr<<<(nnz + 255) / 256, 256, 0, stream>>>(row_idx, nnz, ptr);
        seg_embed_ptr<<<grid, 256, 0, stream>>>(col_idx, data, emb, keep, ptr, out);
    } else {
        seg_embed_bs<<<grid, 256, 0, stream>>>(row_idx, col_idx, data, emb, keep, out, nnz);
    }
}

// Round 3
// 58.292 us; speedup vs baseline: 2.4169x; 1.2034x over previous
//
#include <hip/hip_runtime.h>

#define NUM_IDS   16384
#define EMBED_DIM 128
#define INV_KPROB 1.25f

// ---- workspace layout ----
#define PTR_BYTES  ((size_t)(NUM_IDS + 1) * sizeof(int))
#define PACK_OFF   (((PTR_BYTES) + 255) & ~(size_t)255)
#define PACK_BYTES(nnz) ((size_t)(nnz) * sizeof(int2))

// ============ Kernel 1: row_ptr + packed {col, val} metadata ============
// ptr[r] = first index i with row_idx[i] >= r ; ptr[NUM_IDS] = nnz
// pack[i] = {col, data*1.25} for kept entries, {0, 0.0f} for dropped
// (dropped gathers then hit the cache-hot row 0 and multiply by 0).
__global__ void build_meta(const int*   __restrict__ row_idx,
                           const int*   __restrict__ col_idx,
                           const float* __restrict__ data,
                           const int*   __restrict__ keep,
                           int nnz,
                           int*  __restrict__ ptr,
                           int2* __restrict__ pack) {
    int i = blockIdx.x * blockDim.x + threadIdx.x;
    if (i >= nnz) return;

    const int k = keep[i];
    int2 p;
    p.x = k ? col_idx[i] : 0;
    p.y = __float_as_int(k ? data[i] * INV_KPROB : 0.0f);
    pack[i] = p;

    const int b = row_idx[i];
    if (i == 0) {
        for (int r = 0; r <= b; ++r) ptr[r] = 0;
    } else {
        const int a = row_idx[i - 1];
        for (int r = a + 1; r <= b; ++r) ptr[r] = i;
    }
    if (i == nnz - 1) {
        for (int r = b + 1; r <= NUM_IDS; ++r) ptr[r] = nnz;
    }
}

// ============ Kernel 2: one wave per row, float2 per lane ============
__global__ __launch_bounds__(256) void seg_embed_main(
    const int2*  __restrict__ pack,
    const int*   __restrict__ ptr,
    const float* __restrict__ emb,
    float*       __restrict__ out)
{
    const int lane = threadIdx.x & 63;
    const int wave = threadIdx.x >> 6;
    const int row  = blockIdx.x * 4 + wave;

    // Pin segment bounds to SGPRs -> metadata loads take the scalar path.
    const int start = __builtin_amdgcn_readfirstlane(ptr[row]);
    const int end   = __builtin_amdgcn_readfirstlane(ptr[row + 1]);

    const float* embq = emb + 2 * lane;   // lane covers dims [2*lane, 2*lane+1]
    float ax = 0.f, ay = 0.f;

    int j = start;
    for (; j + 8 <= end; j += 8) {
        float  v[8];
        float2 e[8];
#pragma unroll
        for (int u = 0; u < 8; ++u) {
            const int2 p = pack[j + u];
            v[u] = __int_as_float(p.y);
            e[u] = *reinterpret_cast<const float2*>(
                       embq + (size_t)p.x * EMBED_DIM);
        }
#pragma unroll
        for (int u = 0; u < 8; ++u) {
            ax = fmaf(v[u], e[u].x, ax);
            ay = fmaf(v[u], e[u].y, ay);
        }
    }
    for (; j < end; ++j) {
        const int2 p = pack[j];
        const float  vv = __int_as_float(p.y);
        const float2 e  = *reinterpret_cast<const float2*>(
                              embq + (size_t)p.x * EMBED_DIM);
        ax = fmaf(vv, e.x, ax);
        ay = fmaf(vv, e.y, ay);
    }

    float2 r; r.x = ax; r.y = ay;
    *reinterpret_cast<float2*>(out + (size_t)row * EMBED_DIM + 2 * lane) = r;
}

// ============ Fallback (ws too small): round-2 proven path ============
__device__ __forceinline__ void accum_row_bs(
    int row, int start, int end, int lane,
    const int* __restrict__ col_idx,
    const float* __restrict__ data,
    const int* __restrict__ keep,
    const float* __restrict__ emb,
    float* __restrict__ out)
{
    const int half = lane >> 5;
    const int q    = lane & 31;
    const float* embq = emb + 4 * q;
    float4 acc = make_float4(0.f, 0.f, 0.f, 0.f);

    for (int base = start; base < end; base += 64) {
        const int myi = base + (half << 5) + q;
        int   c = 0;
        float v = 0.f;
        if (myi < end) {
            c = col_idx[myi];
            v = data[myi] * ((float)keep[myi] * INV_KPROB);
        }
        int nh = end - (base + (half << 5));
        if (nh > 32) nh = 32;
        for (int jj = 0; jj < nh; ++jj) {
            const int   src = (half << 5) + jj;
            const int   cj  = __shfl(c, src, 64);
            const float vj  = __shfl(v, src, 64);
            const float4 e  = *reinterpret_cast<const float4*>(
                                  embq + (size_t)cj * EMBED_DIM);
            acc.x = fmaf(vj, e.x, acc.x);
            acc.y = fmaf(vj, e.y, acc.y);
            acc.z = fmaf(vj, e.z, acc.z);
            acc.w = fmaf(vj, e.w, acc.w);
        }
    }
    acc.x += __shfl_xor(acc.x, 32, 64);
    acc.y += __shfl_xor(acc.y, 32, 64);
    acc.z += __shfl_xor(acc.z, 32, 64);
    acc.w += __shfl_xor(acc.w, 32, 64);
    if (half == 0) {
        *reinterpret_cast<float4*>(out + (size_t)row * EMBED_DIM + 4 * q) = acc;
    }
}

__global__ __launch_bounds__(256) void seg_embed_bs(
    const int* __restrict__ row_idx,
    const int* __restrict__ col_idx,
    const float* __restrict__ data,
    const float* __restrict__ emb,
    const int* __restrict__ keep,
    float* __restrict__ out, int nnz)
{
    const int lane = threadIdx.x & 63;
    const int wave = threadIdx.x >> 6;
    const int row  = blockIdx.x * 4 + wave;

    int lo = 0, hi = nnz;
    while (lo < hi) { int m = (lo + hi) >> 1; if (row_idx[m] < row) lo = m + 1; else hi = m; }
    const int start = lo;
    hi = nnz;
    while (lo < hi) { int m = (lo + hi) >> 1; if (row_idx[m] < row + 1) lo = m + 1; else hi = m; }
    const int end = lo;

    accum_row_bs(row, start, end, lane, col_idx, data, keep, emb, out);
}

extern "C" void kernel_launch(void* const* d_in, const int* in_sizes, int n_in,
                              void* d_out, int out_size, void* d_ws, size_t ws_size,
                              hipStream_t stream) {
    const int*   row_idx = (const int*)  d_in[0];
    const int*   col_idx = (const int*)  d_in[1];
    const float* data    = (const float*)d_in[2];
    const float* emb     = (const float*)d_in[3];
    const int*   keep    = (const int*)  d_in[4];
    float*       out     = (float*)d_out;
    const int    nnz     = in_sizes[0];

    const size_t need = PACK_OFF + PACK_BYTES(nnz);
    const int    grid = NUM_IDS / 4;

    if (ws_size >= need) {
        int*  ptr  = (int*)d_ws;
        int2* pack = (int2*)((char*)d_ws + PACK_OFF);
        build_meta<<<(nnz + 255) / 256, 256, 0, stream>>>(
            row_idx, col_idx, data, keep, nnz, ptr, pack);
        seg_embed_main<<<grid, 256, 0, stream>>>(pack, ptr, emb, out);
    } else {
        seg_embed_bs<<<grid, 256, 0, stream>>>(
            row_idx, col_idx, data, emb, keep, out, nnz);
    }
}

// Round 4
// 48.423 us; speedup vs baseline: 2.9094x; 1.2038x over previous
//
#include <hip/hip_runtime.h>

#define NUM_IDS   16384
#define EMBED_DIM 128
#define INV_KPROB 1.25f

// ---------------- helpers ----------------
static __device__ __forceinline__ unsigned short f2bf(float x) {
    unsigned u = __float_as_uint(x);
    unsigned r = (u + 0x7fffu + ((u >> 16) & 1u)) >> 16;   // RNE
    return (unsigned short)r;
}

// ============ Kernel 1: row_ptr + packed {col, val} metadata ============
__global__ void build_meta(const int*   __restrict__ row_idx,
                           const int*   __restrict__ col_idx,
                           const float* __restrict__ data,
                           const int*   __restrict__ keep,
                           int nnz,
                           int*  __restrict__ ptr,
                           int2* __restrict__ pack) {
    int i = blockIdx.x * blockDim.x + threadIdx.x;
    if (i >= nnz) return;

    const int k = keep[i];
    int2 p;
    p.x = k ? col_idx[i] : 0;
    p.y = __float_as_int(k ? data[i] * INV_KPROB : 0.0f);
    pack[i] = p;

    const int b = row_idx[i];
    if (i == 0) {
        for (int r = 0; r <= b; ++r) ptr[r] = 0;
    } else {
        const int a = row_idx[i - 1];
        for (int r = a + 1; r <= b; ++r) ptr[r] = i;
    }
    if (i == nnz - 1) {
        for (int r = b + 1; r <= NUM_IDS; ++r) ptr[r] = nnz;
    }
}

// ============ Kernel 1b: f32 table -> bf16 table (RNE) ============
__global__ __launch_bounds__(256) void conv_bf16(const float* __restrict__ emb,
                                                 unsigned short* __restrict__ tab,
                                                 int n8) {
    int i = blockIdx.x * blockDim.x + threadIdx.x;
    if (i >= n8) return;
    const float4* src = reinterpret_cast<const float4*>(emb) + 2 * (size_t)i;
    float4 a = src[0], b = src[1];
    union { unsigned short u[8]; uint4 v; } r;
    r.u[0] = f2bf(a.x); r.u[1] = f2bf(a.y); r.u[2] = f2bf(a.z); r.u[3] = f2bf(a.w);
    r.u[4] = f2bf(b.x); r.u[5] = f2bf(b.y); r.u[6] = f2bf(b.z); r.u[7] = f2bf(b.w);
    reinterpret_cast<uint4*>(tab)[i] = r.v;
}

// ============ Kernel 2a: bf16 main — quarter-wave per entry ============
// lane = 16*qtr + pos ; pos covers dims [8*pos .. 8*pos+7] (16B of bf16)
__global__ __launch_bounds__(256) void seg_embed_bf16(
    const int2* __restrict__ pack,
    const int*  __restrict__ ptr,
    const unsigned short* __restrict__ tab,
    float* __restrict__ out, int nnz)
{
    const int lane = threadIdx.x & 63;
    const int wave = threadIdx.x >> 6;
    const int row  = blockIdx.x * 4 + wave;
    const int qtr  = lane >> 4;
    const int pos  = lane & 15;

    const int start = __builtin_amdgcn_readfirstlane(ptr[row]);
    const int end   = __builtin_amdgcn_readfirstlane(ptr[row + 1]);

    float acc[8] = {0.f,0.f,0.f,0.f,0.f,0.f,0.f,0.f};

    for (int j = start; j < end; j += 16) {
        int   c[4];
        float v[4];
        uint4 e[4];
#pragma unroll
        for (int u = 0; u < 4; ++u) {
            const int  idx = j + 4 * u + qtr;
            const int  il  = idx < nnz ? idx : nnz - 1;
            const int2 p   = pack[il];
            const bool ok  = idx < end;
            c[u] = ok ? p.x : 0;
            v[u] = ok ? __int_as_float(p.y) : 0.0f;
        }
#pragma unroll
        for (int u = 0; u < 4; ++u) {
            e[u] = *reinterpret_cast<const uint4*>(
                       tab + (size_t)c[u] * EMBED_DIM + 8 * pos);
        }
        __builtin_amdgcn_sched_barrier(0);   // keep all gathers issued before FMAs
#pragma unroll
        for (int u = 0; u < 4; ++u) {
#pragma unroll
            for (int k = 0; k < 4; ++k) {
                const unsigned w  = ((const unsigned*)&e[u])[k];
                const float lo = __uint_as_float(w << 16);
                const float hi = __uint_as_float(w & 0xffff0000u);
                acc[2*k]   = fmaf(v[u], lo, acc[2*k]);
                acc[2*k+1] = fmaf(v[u], hi, acc[2*k+1]);
            }
        }
    }

#pragma unroll
    for (int k = 0; k < 8; ++k) {
        acc[k] += __shfl_xor(acc[k], 16, 64);
        acc[k] += __shfl_xor(acc[k], 32, 64);
    }
    if (qtr == 0) {
        float* o = out + (size_t)row * EMBED_DIM + 8 * pos;
        *reinterpret_cast<float4*>(o)     = make_float4(acc[0], acc[1], acc[2], acc[3]);
        *reinterpret_cast<float4*>(o + 4) = make_float4(acc[4], acc[5], acc[6], acc[7]);
    }
}

// ============ Kernel 2b: f32 main — half-wave per entry (fallback) ======
__global__ __launch_bounds__(256) void seg_embed_f32(
    const int2* __restrict__ pack,
    const int*  __restrict__ ptr,
    const float* __restrict__ emb,
    float* __restrict__ out, int nnz)
{
    const int lane = threadIdx.x & 63;
    const int wave = threadIdx.x >> 6;
    const int row  = blockIdx.x * 4 + wave;
    const int half = lane >> 5;
    const int q    = lane & 31;   // dims [4q..4q+3]

    const int start = __builtin_amdgcn_readfirstlane(ptr[row]);
    const int end   = __builtin_amdgcn_readfirstlane(ptr[row + 1]);

    float4 acc = make_float4(0.f, 0.f, 0.f, 0.f);

    for (int j = start; j < end; j += 8) {
        int    c[4];
        float  v[4];
        float4 e[4];
#pragma unroll
        for (int u = 0; u < 4; ++u) {
            const int  idx = j + 2 * u + half;
            const int  il  = idx < nnz ? idx : nnz - 1;
            const int2 p   = pack[il];
            const bool ok  = idx < end;
            c[u] = ok ? p.x : 0;
            v[u] = ok ? __int_as_float(p.y) : 0.0f;
        }
#pragma unroll
        for (int u = 0; u < 4; ++u) {
            e[u] = *reinterpret_cast<const float4*>(
                       emb + (size_t)c[u] * EMBED_DIM + 4 * q);
        }
        __builtin_amdgcn_sched_barrier(0);
#pragma unroll
        for (int u = 0; u < 4; ++u) {
            acc.x = fmaf(v[u], e[u].x, acc.x);
            acc.y = fmaf(v[u], e[u].y, acc.y);
            acc.z = fmaf(v[u], e[u].z, acc.z);
            acc.w = fmaf(v[u], e[u].w, acc.w);
        }
    }

    acc.x += __shfl_xor(acc.x, 32, 64);
    acc.y += __shfl_xor(acc.y, 32, 64);
    acc.z += __shfl_xor(acc.z, 32, 64);
    acc.w += __shfl_xor(acc.w, 32, 64);
    if (half == 0) {
        *reinterpret_cast<float4*>(out + (size_t)row * EMBED_DIM + 4 * q) = acc;
    }
}

extern "C" void kernel_launch(void* const* d_in, const int* in_sizes, int n_in,
                              void* d_out, int out_size, void* d_ws, size_t ws_size,
                              hipStream_t stream) {
    const int*   row_idx = (const int*)  d_in[0];
    const int*   col_idx = (const int*)  d_in[1];
    const float* data    = (const float*)d_in[2];
    const float* emb     = (const float*)d_in[3];
    const int*   keep    = (const int*)  d_in[4];
    float*       out     = (float*)d_out;
    const int    nnz     = in_sizes[0];
    const int    nitems  = in_sizes[3] / EMBED_DIM;

    const size_t ptr_bytes  = (size_t)(NUM_IDS + 1) * sizeof(int);
    const size_t pack_off   = (ptr_bytes + 255) & ~(size_t)255;
    const size_t pack_bytes = (size_t)nnz * sizeof(int2);
    const size_t tab_off    = (pack_off + pack_bytes + 255) & ~(size_t)255;
    const size_t tab_bytes  = (size_t)nitems * EMBED_DIM * sizeof(unsigned short);

    const int grid = NUM_IDS / 4;

    if (ws_size >= tab_off + tab_bytes) {
        // bf16 path: halve gather bytes, table fits aggregate L2
        int*            ptr  = (int*)d_ws;
        int2*           pack = (int2*)((char*)d_ws + pack_off);
        unsigned short* tab  = (unsigned short*)((char*)d_ws + tab_off);
        const int n8 = nitems * EMBED_DIM / 8;
        build_meta<<<(nnz + 255) / 256, 256, 0, stream>>>(
            row_idx, col_idx, data, keep, nnz, ptr, pack);
        conv_bf16<<<(n8 + 255) / 256, 256, 0, stream>>>(emb, tab, n8);
        seg_embed_bf16<<<grid, 256, 0, stream>>>(pack, ptr, tab, out, nnz);
    } else if (ws_size >= pack_off + pack_bytes) {
        // improved-MLP f32 path
        int*  ptr  = (int*)d_ws;
        int2* pack = (int2*)((char*)d_ws + pack_off);
        build_meta<<<(nnz + 255) / 256, 256, 0, stream>>>(
            row_idx, col_idx, data, keep, nnz, ptr, pack);
        seg_embed_f32<<<grid, 256, 0, stream>>>(pack, ptr, emb, out, nnz);
    }
}